// Round 6
// baseline (138.653 us; speedup 1.0000x reference)
//
#include <hip/hip_runtime.h>

// Batch-as-N MFMA mapping (verified R2-R4): Y^T[j,b] = W^T[j,k] @ H^T[k,b].
// b=lane&15 for the whole net; B-frag k=quad*8+j; D j = t*16 + quad*4 + reg.
//
// R5/R6: gfx950 measured v_exp/v_rcp_f32 ~ 32 issue-cyc/wave64 (R1/R2/R4 all
// sit exactly on that trans roofline). Fix = trans-FREE packed-f16 tanh:
//   tanh(x) = sign(y) * (1-E)/(1+E), E = 2^{-min(|y|,15)}, y = 2*log2e*x
//   2^-k via f16 magic-add bit trick (int ops, both halves in one 32-bit op),
//   2^g (g in [-.5,.5]) deg-3 Taylor, reciprocal of z in [1,2] via 2 Newton.
// MFMA switched bf16 -> f16: tanh outputs (f16 pairs) feed B-frags directly,
// and f16 mantissa (11b vs 8b) cuts the old bf16-dominated absmax ~8x.
// R3 scar: launch_bounds kept relaxed (256,4) so invariants never spill.
// R6 fix: cvt_pkrtz returns __fp16x2, not _Float16x2 -> bit_cast at call sites.

typedef _Float16 h2   __attribute__((ext_vector_type(2)));
typedef _Float16 h8   __attribute__((ext_vector_type(8)));
typedef float    f32x4 __attribute__((ext_vector_type(4)));
typedef unsigned u32x4 __attribute__((ext_vector_type(4)));

#define TANH_SCALE 2.8853900817779268f  // 2*log2(e)

__device__ __forceinline__ h2 h2s(float x) { _Float16 v = (_Float16)x; h2 r = {v, v}; return r; }

// Pack two f32 -> f16 pair (round toward zero) as our h2 type.
__device__ __forceinline__ h2 pk(float a, float b) {
    return __builtin_bit_cast(h2, __builtin_amdgcn_cvt_pkrtz(a, b));
}

// Packed tanh of a PRE-SCALED pair (y = 2*log2e*x). Zero trans ops.
__device__ __forceinline__ h2 tanh2pk(h2 yh) {
    const h2 one = h2s(1.0f), two = h2s(2.0f);
    unsigned yb  = __builtin_bit_cast(unsigned, yh);
    unsigned sgn = yb & 0x80008000u;
    h2 ay = __builtin_bit_cast(h2, yb & 0x7FFF7FFFu);
    h2 v  = __builtin_elementwise_min(ay, h2s(15.0f));   // [0,15]
    h2 Y  = v + h2s(1536.0f);                            // 1536 + round(v), ulp=1
    h2 k  = Y - h2s(1536.0f);                            // round(v), exact
    h2 g  = k - v;                                       // [-0.5,0.5], exact (Sterbenz)
    // bits(Y) = 0x6600 + k per half; (15-k)<<10 = f16 bits of 2^-k.
    // Per-half values <= 15 so one 32-bit sub/shl handles both halves, no borrow/overlap.
    unsigned Sb = (0x660F660Fu - __builtin_bit_cast(unsigned, Y)) << 10;
    h2 S = __builtin_bit_cast(h2, Sb);                   // 2^-k  (k=15 -> +0, saturates)
    // 2^g = e^{g ln2}: deg-3 Taylor, rel err ~9e-4 on [-0.5,0.5]
    h2 p = __builtin_elementwise_fma(g,
             __builtin_elementwise_fma(g,
               __builtin_elementwise_fma(g, h2s(0.0555041f), h2s(0.2402265f)),
               h2s(0.6931472f)), one);
    h2 E = S * p;                                        // 2^{-min(|y|,15)} in (0,1]
    h2 z = E + one;                                      // [1,2]
    h2 r = __builtin_elementwise_fma(E, h2s(-0.5f), one); // r0 = 1-E/2, rel err <=12%
    r = r * __builtin_elementwise_fma(-z, r, two);        // NR1 -> 1.5%
    r = r * __builtin_elementwise_fma(-z, r, two);        // NR2 -> ~2e-4 (+f16 ulp)
    h2 th = __builtin_elementwise_fma(two, r, h2s(-1.0f)); // tanh(|x|) in [0,1)
    return __builtin_bit_cast(h2, __builtin_bit_cast(unsigned, th) | sgn);
}

__global__ __launch_bounds__(256, 4) void damping_mfma(
    const float* __restrict__ x,
    const float* __restrict__ w_d1, const float* __restrict__ w_d2, const float* __restrict__ w_d3,
    const float* __restrict__ w_o1, const float* __restrict__ w_o2, const float* __restrict__ w_o3,
    const float* __restrict__ b_d1, const float* __restrict__ b_d2, const float* __restrict__ b_d3,
    const float* __restrict__ b_o1, const float* __restrict__ b_o2, const float* __restrict__ b_o3,
    float* __restrict__ out, int n_tiles)
{
    const int lane = threadIdx.x & 63;
    const int quad = lane >> 4;
    const int b16  = lane & 15;
    const int wid     = (int)((blockIdx.x * blockDim.x + threadIdx.x) >> 6);
    const int n_waves = (int)((gridDim.x * blockDim.x) >> 6);

    // ---------------- per-lane loop-invariant preload ----------------
    // Layer1 weights in B-frag k-order (k = quad*8 + j), pre-scaled by 2*log2e.
    float w1d0[8], w1d1[8], bd1[8], w1o0[8], w1o1[8], bo1[8];
    #pragma unroll
    for (int j = 0; j < 8; ++j) {
        int k = quad * 8 + j;
        w1d0[j] = w_d1[k] * TANH_SCALE; w1d1[j] = w_d1[32 + k] * TANH_SCALE;
        bd1[j]  = b_d1[k] * TANH_SCALE;
        w1o0[j] = w_o1[k] * TANH_SCALE; w1o1[j] = w_o1[32 + k] * TANH_SCALE;
        bo1[j]  = b_o1[k] * TANH_SCALE;
    }
    // Layer2 A-frags in f16 (pre-scaled): A[m=b16][k=quad*8+j] = S*W^T[j=t*16+m][k]
    h8 a_d2[2], a_o2[2];
    #pragma unroll
    for (int t = 0; t < 2; ++t) {
        #pragma unroll
        for (int j = 0; j < 8; ++j) {
            int k = quad * 8 + j;
            a_d2[t][j] = (_Float16)(w_d2[k * 32 + t * 16 + b16] * TANH_SCALE);
            a_o2[t][j] = (_Float16)(w_o2[k * 32 + t * 16 + b16] * TANH_SCALE);
        }
    }
    // Layer2 bias (pre-scaled) + layer3 weights at this lane's 8 j-values:
    // j = (i>>2)*16 + quad*4 + (i&3)
    float bd2[8], bo2[8], w3d0[8], w3d1[8], w3o[8];
    #pragma unroll
    for (int i = 0; i < 8; ++i) {
        int jj = (i >> 2) * 16 + quad * 4 + (i & 3);
        bd2[i]  = b_d2[jj] * TANH_SCALE; bo2[i] = b_o2[jj] * TANH_SCALE;
        w3d0[i] = w_d3[jj * 2]; w3d1[i] = w_d3[jj * 2 + 1];
        w3o[i]  = w_o3[jj];
    }
    const float bd3_0 = b_d3[0], bd3_1 = b_d3[1], bo3_0 = b_o3[0];

    const float2* x2 = (const float2*)x;

    for (int tile = wid; tile < n_tiles; tile += n_waves) {
        float2 xv = x2[tile * 16 + b16];
        const float x0 = xv.x, x1 = xv.y;

        // -------- layer 1: f32 preacts -> packed f16 tanh, lands in B-frag order --------
        u32x4 bd_, bo_;
        #pragma unroll
        for (int p = 0; p < 4; ++p) {
            float pd0 = fmaf(x1, w1d1[2*p],   fmaf(x0, w1d0[2*p],   bd1[2*p]));
            float pd1 = fmaf(x1, w1d1[2*p+1], fmaf(x0, w1d0[2*p+1], bd1[2*p+1]));
            float po0 = fmaf(x1, w1o1[2*p],   fmaf(x0, w1o0[2*p],   bo1[2*p]));
            float po1 = fmaf(x1, w1o1[2*p+1], fmaf(x0, w1o0[2*p+1], bo1[2*p+1]));
            bd_[p] = __builtin_bit_cast(unsigned, tanh2pk(pk(pd0, pd1)));
            bo_[p] = __builtin_bit_cast(unsigned, tanh2pk(pk(po0, po1)));
        }
        h8 Bd = __builtin_bit_cast(h8, bd_);
        h8 Bo = __builtin_bit_cast(h8, bo_);

        // -------- layer 2: 4 f16 MFMAs (2 j-tiles x 2 branches) --------
        f32x4 zero = {0.f, 0.f, 0.f, 0.f};
        f32x4 d0 = __builtin_amdgcn_mfma_f32_16x16x32_f16(a_d2[0], Bd, zero, 0, 0, 0);
        f32x4 d1 = __builtin_amdgcn_mfma_f32_16x16x32_f16(a_d2[1], Bd, zero, 0, 0, 0);
        f32x4 o0 = __builtin_amdgcn_mfma_f32_16x16x32_f16(a_o2[0], Bo, zero, 0, 0, 0);
        f32x4 o1 = __builtin_amdgcn_mfma_f32_16x16x32_f16(a_o2[1], Bo, zero, 0, 0, 0);

        // -------- layer 2 act (packed tanh) + layer 3 partials --------
        float pd0 = 0.f, pd1 = 0.f, po = 0.f;
        #pragma unroll
        for (int p = 0; p < 4; ++p) {
            int i0 = 2 * p, i1 = 2 * p + 1;
            float vd0 = (i0 < 4 ? d0[i0] : d1[i0 - 4]) + bd2[i0];
            float vd1 = (i1 < 4 ? d0[i1] : d1[i1 - 4]) + bd2[i1];
            float vo0 = (i0 < 4 ? o0[i0] : o1[i0 - 4]) + bo2[i0];
            float vo1 = (i1 < 4 ? o0[i1] : o1[i1 - 4]) + bo2[i1];
            h2 td = tanh2pk(pk(vd0, vd1));
            h2 to = tanh2pk(pk(vo0, vo1));
            pd0 = fmaf((float)td[0], w3d0[i0], fmaf((float)td[1], w3d0[i1], pd0));
            pd1 = fmaf((float)td[0], w3d1[i0], fmaf((float)td[1], w3d1[i1], pd1));
            po  = fmaf((float)to[0], w3o[i0],  fmaf((float)to[1], w3o[i1],  po));
        }
        // butterfly reduce across the 4 quads (same b16)
        pd0 += __shfl_xor(pd0, 16); pd0 += __shfl_xor(pd0, 32);
        pd1 += __shfl_xor(pd1, 16); pd1 += __shfl_xor(pd1, 32);
        po  += __shfl_xor(po, 16);  po  += __shfl_xor(po, 32);

        // -------- epilogue --------
        float d30 = pd0 + bd3_0, d31 = pd1 + bd3_1, c = po + bo3_0;
        float a = (fmaxf(d30, 0.f) + 0.001f) * x0;
        float b = (fmaxf(d31, 0.f) + 0.001f) * x1;
        float D0 = fmaf(a * a, x0, a * c * x1);
        float D1 = fmaf(a * c, x0, fmaf(c, c, b * b) * x1);

        if (quad == 0) ((float2*)out)[tile * 16 + b16] = make_float2(D0, D1);
    }
}

extern "C" void kernel_launch(void* const* d_in, const int* in_sizes, int n_in,
                              void* d_out, int out_size, void* d_ws, size_t ws_size,
                              hipStream_t stream) {
    const float* x    = (const float*)d_in[0];
    const float* w_d1 = (const float*)d_in[1];
    const float* w_d2 = (const float*)d_in[2];
    const float* w_d3 = (const float*)d_in[3];
    const float* w_o1 = (const float*)d_in[4];
    const float* w_o2 = (const float*)d_in[5];
    const float* w_o3 = (const float*)d_in[6];
    const float* b_d1 = (const float*)d_in[7];
    const float* b_d2 = (const float*)d_in[8];
    const float* b_d3 = (const float*)d_in[9];
    const float* b_o1 = (const float*)d_in[10];
    const float* b_o2 = (const float*)d_in[11];
    const float* b_o3 = (const float*)d_in[12];
    float* out = (float*)d_out;

    int n = in_sizes[0] / 2;         // rows
    int n_tiles = n / 16;            // 16 rows per wave-iteration
    int blocks_needed = (n_tiles + 3) / 4;
    int grid = blocks_needed < 1792 ? blocks_needed : 1792;  // 7168 waves = 7/SIMD
    damping_mfma<<<grid, 256, 0, stream>>>(
        x, w_d1, w_d2, w_d3, w_o1, w_o2, w_o3,
        b_d1, b_d2, b_d3, b_o1, b_o2, b_o3, out, n_tiles);
}

// Round 7
// 137.178 us; speedup vs baseline: 1.0107x; 1.0107x over previous
//
#include <hip/hip_runtime.h>

// Batch-as-N MFMA mapping (verified R2-R6): Y^T[j,b] = W^T[j,k] @ H^T[k,b].
// b=lane&15 for the whole net; B-frag k=quad*8+j; D j = t*16 + quad*4 + reg.
//
// Pipe model from R4/R6 counters:
//   - trans pipe: ~32 cyc per wave64 v_exp/v_rcp (R4 wall = 64 trans x 32 exactly)
//   - packed f16 VALU: ~2x slower than hoped (R6 regression) -> no f16 math
// R7: balance both pipes. tanh = 1 trans + ~9 f32 VALU:
//   y = 2*log2e*x (scale folded into weights/biases)
//   E = exp2(-|y|)            <- ONE trans op, -|y| via free src modifier
//   tanh(|x|) = 1 - 2E/(1+E)  <- division by z=1+E in [1,2] via 2 Newton steps
//                                (seed 1-E/2: err .125 -> 1.6e-2 -> 2.4e-4)
//   sign restored with one v_bfi (copysign)
// Layer2 activations stay f32 through layer3 (no cvt). B-frags packed f16 only
// at the MFMA boundary. R3 scar: launch_bounds relaxed (256,4) - never spill.

typedef _Float16 h2   __attribute__((ext_vector_type(2)));
typedef _Float16 h8   __attribute__((ext_vector_type(8)));
typedef float    f32x4 __attribute__((ext_vector_type(4)));
typedef unsigned u32x4 __attribute__((ext_vector_type(4)));

#define TANH_SCALE 2.8853900817779268f  // 2*log2(e)

// Pack two f32 -> f16 pair (round toward zero).
__device__ __forceinline__ h2 pk(float a, float b) {
    return __builtin_bit_cast(h2, __builtin_amdgcn_cvt_pkrtz(a, b));
}

// tanh of PRE-SCALED y = 2*log2e*x. 1 trans + ~9 VALU, rel err ~2.4e-4.
__device__ __forceinline__ float tanh_pre(float y) {
    float E = __builtin_amdgcn_exp2f(-__builtin_fabsf(y));  // modifier-folded
    float z = E + 1.0f;                                     // [1,2]
    float r = __builtin_fmaf(E, -0.5f, 1.0f);               // seed 1/z, err<=12.5%
    r = r * __builtin_fmaf(-z, r, 2.0f);                    // NR1 -> 1.6e-2
    r = r * __builtin_fmaf(-z, r, 2.0f);                    // NR2 -> 2.4e-4
    float th = __builtin_fmaf(-2.0f * E, r, 1.0f);          // tanh(|x|)
    return __builtin_copysignf(th, y);                      // v_bfi
}

__global__ __launch_bounds__(256, 4) void damping_mfma(
    const float* __restrict__ x,
    const float* __restrict__ w_d1, const float* __restrict__ w_d2, const float* __restrict__ w_d3,
    const float* __restrict__ w_o1, const float* __restrict__ w_o2, const float* __restrict__ w_o3,
    const float* __restrict__ b_d1, const float* __restrict__ b_d2, const float* __restrict__ b_d3,
    const float* __restrict__ b_o1, const float* __restrict__ b_o2, const float* __restrict__ b_o3,
    float* __restrict__ out, int n_tiles)
{
    const int lane = threadIdx.x & 63;
    const int quad = lane >> 4;
    const int b16  = lane & 15;
    const int wid     = (int)((blockIdx.x * blockDim.x + threadIdx.x) >> 6);
    const int n_waves = (int)((gridDim.x * blockDim.x) >> 6);

    // ---------------- per-lane loop-invariant preload ----------------
    // Layer1 weights in B-frag k-order (k = quad*8 + j), pre-scaled by 2*log2e.
    float w1d0[8], w1d1[8], bd1[8], w1o0[8], w1o1[8], bo1[8];
    #pragma unroll
    for (int j = 0; j < 8; ++j) {
        int k = quad * 8 + j;
        w1d0[j] = w_d1[k] * TANH_SCALE; w1d1[j] = w_d1[32 + k] * TANH_SCALE;
        bd1[j]  = b_d1[k] * TANH_SCALE;
        w1o0[j] = w_o1[k] * TANH_SCALE; w1o1[j] = w_o1[32 + k] * TANH_SCALE;
        bo1[j]  = b_o1[k] * TANH_SCALE;
    }
    // Layer2 A-frags in f16 (pre-scaled): A[m=b16][k=quad*8+j] = S*W^T[j=t*16+m][k]
    h8 a_d2[2], a_o2[2];
    #pragma unroll
    for (int t = 0; t < 2; ++t) {
        #pragma unroll
        for (int j = 0; j < 8; ++j) {
            int k = quad * 8 + j;
            a_d2[t][j] = (_Float16)(w_d2[k * 32 + t * 16 + b16] * TANH_SCALE);
            a_o2[t][j] = (_Float16)(w_o2[k * 32 + t * 16 + b16] * TANH_SCALE);
        }
    }
    // Layer2 bias (pre-scaled) + layer3 weights at this lane's 8 j-values:
    // j = (i>>2)*16 + quad*4 + (i&3)
    float bd2[8], bo2[8], w3d0[8], w3d1[8], w3o[8];
    #pragma unroll
    for (int i = 0; i < 8; ++i) {
        int jj = (i >> 2) * 16 + quad * 4 + (i & 3);
        bd2[i]  = b_d2[jj] * TANH_SCALE; bo2[i] = b_o2[jj] * TANH_SCALE;
        w3d0[i] = w_d3[jj * 2]; w3d1[i] = w_d3[jj * 2 + 1];
        w3o[i]  = w_o3[jj];
    }
    const float bd3_0 = b_d3[0], bd3_1 = b_d3[1], bo3_0 = b_o3[0];

    const float2* x2 = (const float2*)x;

    for (int tile = wid; tile < n_tiles; tile += n_waves) {
        float2 xv = x2[tile * 16 + b16];
        const float x0 = xv.x, x1 = xv.y;

        // -------- layer 1: f32 preact -> f32 tanh (1 trans each) --------
        float hd[8], ho[8];
        #pragma unroll
        for (int j = 0; j < 8; ++j) {
            hd[j] = tanh_pre(fmaf(x1, w1d1[j], fmaf(x0, w1d0[j], bd1[j])));
            ho[j] = tanh_pre(fmaf(x1, w1o1[j], fmaf(x0, w1o0[j], bo1[j])));
        }
        // pack to f16 B-frags at the MFMA boundary only
        u32x4 bd_, bo_;
        #pragma unroll
        for (int p = 0; p < 4; ++p) {
            bd_[p] = __builtin_bit_cast(unsigned, pk(hd[2*p], hd[2*p+1]));
            bo_[p] = __builtin_bit_cast(unsigned, pk(ho[2*p], ho[2*p+1]));
        }
        h8 Bd = __builtin_bit_cast(h8, bd_);
        h8 Bo = __builtin_bit_cast(h8, bo_);

        // -------- layer 2: 4 f16 MFMAs (2 j-tiles x 2 branches) --------
        f32x4 zero = {0.f, 0.f, 0.f, 0.f};
        f32x4 d0 = __builtin_amdgcn_mfma_f32_16x16x32_f16(a_d2[0], Bd, zero, 0, 0, 0);
        f32x4 d1 = __builtin_amdgcn_mfma_f32_16x16x32_f16(a_d2[1], Bd, zero, 0, 0, 0);
        f32x4 o0 = __builtin_amdgcn_mfma_f32_16x16x32_f16(a_o2[0], Bo, zero, 0, 0, 0);
        f32x4 o1 = __builtin_amdgcn_mfma_f32_16x16x32_f16(a_o2[1], Bo, zero, 0, 0, 0);

        // -------- layer 2 act (f32 tanh) + layer 3 partials (all f32) --------
        float pd0 = 0.f, pd1 = 0.f, po = 0.f;
        #pragma unroll
        for (int i = 0; i < 8; ++i) {
            float vd = (i < 4 ? d0[i] : d1[i - 4]) + bd2[i];
            float vo = (i < 4 ? o0[i] : o1[i - 4]) + bo2[i];
            float h2d = tanh_pre(vd);
            float h2o = tanh_pre(vo);
            pd0 = fmaf(h2d, w3d0[i], pd0);
            pd1 = fmaf(h2d, w3d1[i], pd1);
            po  = fmaf(h2o, w3o[i], po);
        }
        // butterfly reduce across the 4 quads (same b16)
        pd0 += __shfl_xor(pd0, 16); pd0 += __shfl_xor(pd0, 32);
        pd1 += __shfl_xor(pd1, 16); pd1 += __shfl_xor(pd1, 32);
        po  += __shfl_xor(po, 16);  po  += __shfl_xor(po, 32);

        // -------- epilogue --------
        float d30 = pd0 + bd3_0, d31 = pd1 + bd3_1, c = po + bo3_0;
        float a = (fmaxf(d30, 0.f) + 0.001f) * x0;
        float b = (fmaxf(d31, 0.f) + 0.001f) * x1;
        float D0 = fmaf(a * a, x0, a * c * x1);
        float D1 = fmaf(a * c, x0, fmaf(c, c, b * b) * x1);

        if (quad == 0) ((float2*)out)[tile * 16 + b16] = make_float2(D0, D1);
    }
}

extern "C" void kernel_launch(void* const* d_in, const int* in_sizes, int n_in,
                              void* d_out, int out_size, void* d_ws, size_t ws_size,
                              hipStream_t stream) {
    const float* x    = (const float*)d_in[0];
    const float* w_d1 = (const float*)d_in[1];
    const float* w_d2 = (const float*)d_in[2];
    const float* w_d3 = (const float*)d_in[3];
    const float* w_o1 = (const float*)d_in[4];
    const float* w_o2 = (const float*)d_in[5];
    const float* w_o3 = (const float*)d_in[6];
    const float* b_d1 = (const float*)d_in[7];
    const float* b_d2 = (const float*)d_in[8];
    const float* b_d3 = (const float*)d_in[9];
    const float* b_o1 = (const float*)d_in[10];
    const float* b_o2 = (const float*)d_in[11];
    const float* b_o3 = (const float*)d_in[12];
    float* out = (float*)d_out;

    int n = in_sizes[0] / 2;         // rows
    int n_tiles = n / 16;            // 16 rows per wave-iteration
    int blocks_needed = (n_tiles + 3) / 4;
    int grid = blocks_needed < 1792 ? blocks_needed : 1792;  // 7168 waves = 7/SIMD
    damping_mfma<<<grid, 256, 0, stream>>>(
        x, w_d1, w_d2, w_d3, w_o1, w_o2, w_o3,
        b_d1, b_d2, b_d3, b_o1, b_o2, b_o3, out, n_tiles);
}